// Round 1
// baseline (742.834 us; speedup 1.0000x reference)
//
#include <hip/hip_runtime.h>
#include <math.h>

// Problem constants (fixed by setup_inputs)
#define NN   256   // N rows
#define CCH  512   // C features
#define MMM  64    // M slices
#define KPOS 8     // K positives
#define MARG 0.2f

// Workspace layout (bytes). Requires ws_size >= ~34.2 MB.
#define XT_OFF   ((size_t)0)
#define XT_BYTES ((size_t)MMM * NN * CCH * 4)                  // 33,554,432
#define X2_OFF   (XT_OFF + XT_BYTES)                           // 64*256*4
#define DAP_OFF  (X2_OFF + (size_t)MMM * NN * 4)               // 64*256*8*4
#define POS_OFF  (DAP_OFF + (size_t)MMM * NN * KPOS * 4)       // 256*8*4
#define NEG_OFF  (POS_OFF + (size_t)NN * KPOS * 4)             // 256*4*8
#define S_OFF    (NEG_OFF + (size_t)NN * 4 * 8)                // 64*4
#define CNT_OFF  (S_OFF + (size_t)MMM * 4)                     // 64*4

// ---------------------------------------------------------------------------
// Kernel P: stable-argsort semantics -> pos_idx[n][8], neg bitmask[n][4 u64].
// Also zeroes the per-m accumulators (must run every launch: harness poisons
// ws once and never re-poisons between replays).
// ---------------------------------------------------------------------------
__global__ void kP(const int* __restrict__ label, int* __restrict__ pos_idx,
                   unsigned long long* __restrict__ neg_mask,
                   float* __restrict__ s_acc, unsigned int* __restrict__ c_acc) {
  int n = threadIdx.x;
  if (n < MMM) { s_acc[n] = 0.0f; c_acc[n] = 0u; }
  if (n >= NN) return;
  int lab = label[n];
  int P = 0;
  for (int k = 0; k < NN; ++k) P += (label[k] == lab) ? 1 : 0;
  unsigned long long mask[4] = {0ull, 0ull, 0ull, 0ull};
  int pr = 0, nr = 0;
  for (int k = 0; k < NN; ++k) {
    // stable order: all positives (ascending k), then all negatives (ascending k)
    int r = (label[k] == lab) ? (pr++) : (P + nr++);
    if (r < KPOS) pos_idx[n * KPOS + r] = k;
    else          mask[k >> 6] |= (1ull << (k & 63));
  }
  #pragma unroll
  for (int w = 0; w < 4; ++w) neg_mask[n * 4 + w] = mask[w];
}

// ---------------------------------------------------------------------------
// Kernel T: transpose feature (N,C,M) -> Xt (M,N,C). Coalesced both sides via
// a 64c x 64m LDS tile (pad 65 to kill read bank conflicts).
// ---------------------------------------------------------------------------
__global__ void kT(const float* __restrict__ f, float* __restrict__ Xt) {
  __shared__ float tile[64][65];
  int bid = blockIdx.x;
  int n  = bid >> 3;
  int c0 = (bid & 7) << 6;
  int t = threadIdx.x;
  int ml = t & 63, cg = t >> 6;
  const float* src = f + (size_t)n * CCH * MMM + (size_t)c0 * MMM + ml;
  #pragma unroll
  for (int i = 0; i < 16; ++i) {
    int cl = cg * 16 + i;
    tile[cl][ml] = src[(size_t)cl * MMM];   // 64 lanes contiguous over m
  }
  __syncthreads();
  int cl2 = t & 63, mg = t >> 6;
  #pragma unroll
  for (int i = 0; i < 16; ++i) {
    int mrow = mg * 16 + i;
    Xt[(size_t)mrow * NN * CCH + (size_t)n * CCH + c0 + cl2] = tile[cl2][mrow];
  }
}

// One wave computes dot(a,b) over 512 floats; valid on lane 0.
// IMPORTANT: fixed op order so kA1(self) and kA2(n==pk) agree bitwise
// -> diagonal d2 is exactly 0, matching safe_sqrt semantics.
__device__ __forceinline__ float rowdot(const float* __restrict__ a,
                                        const float* __restrict__ b, int lane) {
  const float4* a4 = (const float4*)(a + lane * 8);
  const float4* b4 = (const float4*)(b + lane * 8);
  float4 x0 = a4[0], x1 = a4[1];
  float4 y0 = b4[0], y1 = b4[1];
  float p = x0.x * y0.x + x0.y * y0.y + x0.z * y0.z + x0.w * y0.w
          + x1.x * y1.x + x1.y * y1.y + x1.z * y1.z + x1.w * y1.w;
  #pragma unroll
  for (int off = 32; off > 0; off >>= 1) p += __shfl_down(p, off, 64);
  return p;
}

// Kernel A1: x2[m][n] = |x_mn|^2 (fp32). One block per m, 4 waves.
__global__ void kA1(const float* __restrict__ Xt, float* __restrict__ x2) {
  int m = blockIdx.x;
  int w = threadIdx.x >> 6, lane = threadIdx.x & 63;
  const float* base = Xt + (size_t)m * NN * CCH;
  for (int i = 0; i < 64; ++i) {
    int n = w * 64 + i;
    float d = rowdot(base + (size_t)n * CCH, base + (size_t)n * CCH, lane);
    if (lane == 0) x2[m * NN + n] = d;
  }
}

// Kernel A2: dap[m][n][p] = dist(n, pos_idx[n][p]) in exact fp32.
__global__ void kA2(const float* __restrict__ Xt, const float* __restrict__ x2,
                    const int* __restrict__ pos_idx, float* __restrict__ dap) {
  int b = blockIdx.x;
  int m = b >> 3, n0 = (b & 7) * 32;
  int w = threadIdx.x >> 6, lane = threadIdx.x & 63;
  const float* base = Xt + (size_t)m * NN * CCH;
  for (int i = 0; i < 64; ++i) {
    int q = w * 64 + i;               // 256 (n,p) tasks per block, 64 per wave
    int n = n0 + (q >> 3), p = q & 7;
    int pk = pos_idx[n * KPOS + p];
    float d = rowdot(base + (size_t)n * CCH, base + (size_t)pk * CCH, lane);
    if (lane == 0) {
      float z = x2[m * NN + n] + x2[m * NN + pk] - 2.0f * d;
      dap[(m * NN + n) * KPOS + p] = (z > 0.0f) ? sqrtf(z) : 0.0f;
    }
  }
}

// ---------------------------------------------------------------------------
// Kernel B: fused Gram(128x128 tile) -> dist -> triplet loss accumulate.
// grid = 64 m * 2 * 2 tiles = 256 blocks (1/CU), 256 threads, 8x8/thread.
// LDS: XOR-swizzled (c4 ^ (row&7)) row-major tiles, reg double-buffered.
// ---------------------------------------------------------------------------
#define TB 128
#define CB 32
__global__ __launch_bounds__(256) void kB(
    const float* __restrict__ Xt, const float* __restrict__ x2,
    const float* __restrict__ dap, const unsigned long long* __restrict__ neg_mask,
    float* __restrict__ s_acc, unsigned int* __restrict__ c_acc) {
  __shared__ float As[TB * CB];
  __shared__ float Bs[TB * CB];
  __shared__ float red_s[4];
  __shared__ unsigned int red_c[4];

  int bid = blockIdx.x;
  int m  = bid >> 2;
  int tn = (bid >> 1) & 1, tk = bid & 1;
  int n0 = tn * TB, k0 = tk * TB;
  int t  = threadIdx.x;
  int tx = t & 15, ty = t >> 4;
  const float* Abase = Xt + (size_t)m * NN * CCH + (size_t)n0 * CCH;
  const float* Bbase = Xt + (size_t)m * NN * CCH + (size_t)k0 * CCH;

  float4 stA[4], stB[4];
  float acc[8][8];
  #pragma unroll
  for (int i = 0; i < 8; ++i)
    #pragma unroll
    for (int j = 0; j < 8; ++j) acc[i][j] = 0.0f;

  // float4-slot within swizzled LDS tile: row stride = 8 slots (32 floats)
  auto ldsIdx = [](int row, int c4) { return row * 8 + (c4 ^ (row & 7)); };

  auto loadRegs = [&](int ch) {
    int c0 = ch * CB;
    #pragma unroll
    for (int i = 0; i < 4; ++i) {
      int fid = t + 256 * i;            // 1024 float4 per tile
      int row = fid >> 3, c4 = fid & 7; // lane-consecutive -> coalesced
      stA[i] = *(const float4*)(Abase + (size_t)row * CCH + c0 + c4 * 4);
      stB[i] = *(const float4*)(Bbase + (size_t)row * CCH + c0 + c4 * 4);
    }
  };
  auto writeLds = [&]() {
    #pragma unroll
    for (int i = 0; i < 4; ++i) {
      int fid = t + 256 * i;
      int row = fid >> 3, c4 = fid & 7;
      ((float4*)As)[ldsIdx(row, c4)] = stA[i];
      ((float4*)Bs)[ldsIdx(row, c4)] = stB[i];
    }
  };
  auto computeChunk = [&]() {
    #pragma unroll
    for (int c4 = 0; c4 < 8; ++c4) {
      float4 av[8], bv[8];
      #pragma unroll
      for (int ii = 0; ii < 8; ++ii) {
        int row = ii * 16 + ty;                      // broadcast across tx
        av[ii] = ((const float4*)As)[ldsIdx(row, c4)];
      }
      #pragma unroll
      for (int jj = 0; jj < 8; ++jj) {
        int row = jj * 16 + tx;                      // swizzle spreads banks
        bv[jj] = ((const float4*)Bs)[ldsIdx(row, c4)];
      }
      #pragma unroll
      for (int ii = 0; ii < 8; ++ii)
        #pragma unroll
        for (int jj = 0; jj < 8; ++jj)
          acc[ii][jj] += av[ii].x * bv[jj].x + av[ii].y * bv[jj].y
                       + av[ii].z * bv[jj].z + av[ii].w * bv[jj].w;
    }
  };

  loadRegs(0);
  writeLds();
  __syncthreads();
  for (int ch = 1; ch < CCH / CB; ++ch) {
    loadRegs(ch);       // prefetch next chunk into regs (overlaps compute)
    computeChunk();     // consume LDS chunk ch-1
    __syncthreads();
    writeLds();
    __syncthreads();
  }
  computeChunk();

  // Fused epilogue: dist + masked 8-way relu accumulate.
  float ls = 0.0f; unsigned int lc = 0u;
  #pragma unroll
  for (int ii = 0; ii < 8; ++ii) {
    int n = n0 + ii * 16 + ty;
    float x2n = x2[m * NN + n];
    float dv[KPOS];
    #pragma unroll
    for (int p = 0; p < KPOS; ++p) dv[p] = dap[(m * NN + n) * KPOS + p];
    unsigned long long nm0 = neg_mask[n * 4 + ((k0 + tx) >> 6)];     // k block
    unsigned long long nm1 = neg_mask[n * 4 + ((k0 + 64 + tx) >> 6)];
    #pragma unroll
    for (int jj = 0; jj < 8; ++jj) {
      int k = k0 + jj * 16 + tx;
      float z = x2n + x2[m * NN + k] - 2.0f * acc[ii][jj];
      float dist = (z > 0.0f) ? sqrtf(z) : 0.0f;
      unsigned long long nm = (jj < 4) ? nm0 : nm1;
      bool isneg = (nm >> (k & 63)) & 1ull;
      if (isneg) {
        #pragma unroll
        for (int p = 0; p < KPOS; ++p) {
          float tt = MARG + dv[p] - dist;
          if (tt > 0.0f) { ls += tt; lc++; }
        }
      }
    }
  }
  #pragma unroll
  for (int off = 32; off > 0; off >>= 1) {
    ls += __shfl_down(ls, off, 64);
    lc += __shfl_down(lc, off, 64);
  }
  int lane = t & 63, w = t >> 6;
  if (lane == 0) { red_s[w] = ls; red_c[w] = lc; }
  __syncthreads();
  if (t == 0) {
    float S = red_s[0] + red_s[1] + red_s[2] + red_s[3];
    unsigned int Cn = red_c[0] + red_c[1] + red_c[2] + red_c[3];
    atomicAdd(&s_acc[m], S);
    atomicAdd(&c_acc[m], Cn);
  }
}

// Kernel C: finalize the two scalars.
__global__ void kC(const float* __restrict__ s_acc,
                   const unsigned int* __restrict__ c_acc,
                   float* __restrict__ out) {
  int t = threadIdx.x;  // 64 threads = 1 wave
  float c  = (float)c_acc[t];
  float sm = s_acc[t];
  float mean = (c > 0.0f) ? (sm / c) : 0.0f;
  float csum = c;
  #pragma unroll
  for (int off = 32; off > 0; off >>= 1) {
    mean += __shfl_down(mean, off, 64);
    csum += __shfl_down(csum, off, 64);
  }
  if (t == 0) {
    out[0] = mean / 64.0f;
    // lm.size = M * N * K * (N-K) = 64*256*8*248 = 32,505,856 (full size!)
    out[1] = (csum / 64.0f) / 32505856.0f;
  }
}

extern "C" void kernel_launch(void* const* d_in, const int* in_sizes, int n_in,
                              void* d_out, int out_size, void* d_ws, size_t ws_size,
                              hipStream_t stream) {
  const float* feature = (const float*)d_in[0];
  const int*   label   = (const int*)d_in[1];
  char* w = (char*)d_ws;
  float* Xt  = (float*)(w + XT_OFF);
  float* x2  = (float*)(w + X2_OFF);
  float* dap = (float*)(w + DAP_OFF);
  int*   pos = (int*)(w + POS_OFF);
  unsigned long long* neg = (unsigned long long*)(w + NEG_OFF);
  float* s_acc = (float*)(w + S_OFF);
  unsigned int* c_acc = (unsigned int*)(w + CNT_OFF);
  float* out = (float*)d_out;

  kP <<<1,    256, 0, stream>>>(label, pos, neg, s_acc, c_acc);
  kT <<<2048, 256, 0, stream>>>(feature, Xt);
  kA1<<<64,   256, 0, stream>>>(Xt, x2);
  kA2<<<512,  256, 0, stream>>>(Xt, x2, pos, dap);
  kB <<<256,  256, 0, stream>>>(Xt, x2, dap, neg, s_acc, c_acc);
  kC <<<1,    64,  0, stream>>>(s_acc, c_acc, out);
}

// Round 2
// 683.075 us; speedup vs baseline: 1.0875x; 1.0875x over previous
//
#include <hip/hip_runtime.h>
#include <math.h>

// Problem constants (fixed by setup_inputs)
#define NN   256   // N rows
#define CCH  512   // C features
#define MMM  64    // M slices
#define KPOS 8     // K positives
#define MARG 0.2f

// Workspace layout (bytes). Requires ws_size >= ~34.2 MB.
#define XT_OFF   ((size_t)0)
#define XT_BYTES ((size_t)MMM * NN * CCH * 4)                  // 33,554,432
#define X2_OFF   (XT_OFF + XT_BYTES)
#define DAP_OFF  (X2_OFF + (size_t)MMM * NN * 4)
#define POS_OFF  (DAP_OFF + (size_t)MMM * NN * KPOS * 4)
#define NEG_OFF  (POS_OFF + (size_t)NN * KPOS * 4)
#define S_OFF    (NEG_OFF + (size_t)NN * 4 * 8)
#define CNT_OFF  (S_OFF + (size_t)MMM * 4)

// async global->LDS, 16B per lane, LDS dest is wave-uniform base + lane*16
#define GLD_LDS16(gp, lp) __builtin_amdgcn_global_load_lds(                 \
    (const __attribute__((address_space(1))) void*)(gp),                    \
    (__attribute__((address_space(3))) void*)(lp), 16, 0, 0)

// ---------------------------------------------------------------------------
// Kernel P: stable-argsort semantics -> pos_idx[n][8], neg bitmask[n][4 u64].
// Also zeroes the per-m accumulators (ws is poisoned once, never re-poisoned).
// ---------------------------------------------------------------------------
__global__ void kP(const int* __restrict__ label, int* __restrict__ pos_idx,
                   unsigned long long* __restrict__ neg_mask,
                   float* __restrict__ s_acc, unsigned int* __restrict__ c_acc) {
  int n = threadIdx.x;
  if (n < MMM) { s_acc[n] = 0.0f; c_acc[n] = 0u; }
  if (n >= NN) return;
  int lab = label[n];
  int P = 0;
  for (int k = 0; k < NN; ++k) P += (label[k] == lab) ? 1 : 0;
  unsigned long long mask[4] = {0ull, 0ull, 0ull, 0ull};
  int pr = 0, nr = 0;
  for (int k = 0; k < NN; ++k) {
    int r = (label[k] == lab) ? (pr++) : (P + nr++);
    if (r < KPOS) pos_idx[n * KPOS + r] = k;
    else          mask[k >> 6] |= (1ull << (k & 63));
  }
  #pragma unroll
  for (int w = 0; w < 4; ++w) neg_mask[n * 4 + w] = mask[w];
}

// ---------------------------------------------------------------------------
// Kernel T: transpose feature (N,C,M) -> Xt (M,N,C).
// ---------------------------------------------------------------------------
__global__ void kT(const float* __restrict__ f, float* __restrict__ Xt) {
  __shared__ float tile[64][65];
  int bid = blockIdx.x;
  int n  = bid >> 3;
  int c0 = (bid & 7) << 6;
  int t = threadIdx.x;
  int ml = t & 63, cg = t >> 6;
  const float* src = f + (size_t)n * CCH * MMM + (size_t)c0 * MMM + ml;
  #pragma unroll
  for (int i = 0; i < 16; ++i) {
    int cl = cg * 16 + i;
    tile[cl][ml] = src[(size_t)cl * MMM];
  }
  __syncthreads();
  int cl2 = t & 63, mg = t >> 6;
  #pragma unroll
  for (int i = 0; i < 16; ++i) {
    int mrow = mg * 16 + i;
    Xt[(size_t)mrow * NN * CCH + (size_t)n * CCH + c0 + cl2] = tile[cl2][mrow];
  }
}

// One wave computes dot(a,b) over 512 floats; valid on lane 0.
// Fixed op order so kA1(self) and kA2(n==pk) agree bitwise -> diagonal d2 == 0.
__device__ __forceinline__ float rowdot(const float* __restrict__ a,
                                        const float* __restrict__ b, int lane) {
  const float4* a4 = (const float4*)(a + lane * 8);
  const float4* b4 = (const float4*)(b + lane * 8);
  float4 x0 = a4[0], x1 = a4[1];
  float4 y0 = b4[0], y1 = b4[1];
  float p = x0.x * y0.x + x0.y * y0.y + x0.z * y0.z + x0.w * y0.w
          + x1.x * y1.x + x1.y * y1.y + x1.z * y1.z + x1.w * y1.w;
  #pragma unroll
  for (int off = 32; off > 0; off >>= 1) p += __shfl_down(p, off, 64);
  return p;
}

// Kernel A1: x2[m][n] = |x_mn|^2 (fp32).
__global__ void kA1(const float* __restrict__ Xt, float* __restrict__ x2) {
  int m = blockIdx.x;
  int w = threadIdx.x >> 6, lane = threadIdx.x & 63;
  const float* base = Xt + (size_t)m * NN * CCH;
  for (int i = 0; i < 64; ++i) {
    int n = w * 64 + i;
    float d = rowdot(base + (size_t)n * CCH, base + (size_t)n * CCH, lane);
    if (lane == 0) x2[m * NN + n] = d;
  }
}

// Kernel A2: dap[m][n][p] = dist(n, pos_idx[n][p]) in exact fp32.
__global__ void kA2(const float* __restrict__ Xt, const float* __restrict__ x2,
                    const int* __restrict__ pos_idx, float* __restrict__ dap) {
  int b = blockIdx.x;
  int m = b >> 3, n0 = (b & 7) * 32;
  int w = threadIdx.x >> 6, lane = threadIdx.x & 63;
  const float* base = Xt + (size_t)m * NN * CCH;
  for (int i = 0; i < 64; ++i) {
    int q = w * 64 + i;
    int n = n0 + (q >> 3), p = q & 7;
    int pk = pos_idx[n * KPOS + p];
    float d = rowdot(base + (size_t)n * CCH, base + (size_t)pk * CCH, lane);
    if (lane == 0) {
      float z = x2[m * NN + n] + x2[m * NN + pk] - 2.0f * d;
      dap[(m * NN + n) * KPOS + p] = (z > 0.0f) ? sqrtf(z) : 0.0f;
    }
  }
}

// ---------------------------------------------------------------------------
// Kernel B: fused Gram(128x128 tile) -> dist -> triplet loss accumulate.
// Staging via global_load_lds (width 16), swizzle applied on the GLOBAL source
// address (LDS dest must be linear); reads apply the same XOR involution.
// Double-buffered LDS (64 KB), 2-deep prefetch, one barrier per chunk.
// Per-thread live set: acc[8][8] (64) + av[8] (32) + streamed bv -> no spills.
// ---------------------------------------------------------------------------
#define TB 128
#define CB 32
#define CHUNKS (CCH / CB)   // 16
__global__ __launch_bounds__(256) void kB(
    const float* __restrict__ Xt, const float* __restrict__ x2,
    const float* __restrict__ dap, const unsigned long long* __restrict__ neg_mask,
    float* __restrict__ s_acc, unsigned int* __restrict__ c_acc) {
  __shared__ float As[2][TB * CB];   // 2 x 16 KB
  __shared__ float Bs[2][TB * CB];   // 2 x 16 KB  (total exactly 64 KB)

  int bid = blockIdx.x;
  int m  = bid >> 2;
  int tn = (bid >> 1) & 1, tk = bid & 1;
  int n0 = tn * TB, k0 = tk * TB;
  int t  = threadIdx.x;
  int tx = t & 15, ty = t >> 4;
  const float* Abase = Xt + (size_t)m * NN * CCH + (size_t)n0 * CCH;
  const float* Bbase = Xt + (size_t)m * NN * CCH + (size_t)k0 * CCH;

  float acc[8][8];
  #pragma unroll
  for (int i = 0; i < 8; ++i)
    #pragma unroll
    for (int j = 0; j < 8; ++j) acc[i][j] = 0.0f;

  // Stage chunk ch into buffer buf. LDS slot fid (linear) receives global
  // element (row = fid>>3, c4 = (fid&7) ^ (row&7)).
  auto stage = [&](int buf, int ch) {
    int c0 = ch * CB;
    #pragma unroll
    for (int i = 0; i < 4; ++i) {
      int fid = t + 256 * i;            // float4 slot 0..1023
      int row = fid >> 3;
      int c4g = (fid & 7) ^ (row & 7);  // inverse-swizzled source column
      int bslot = fid & ~63;            // wave-uniform LDS base slot
      GLD_LDS16(Abase + (size_t)row * CCH + c0 + c4g * 4, &As[buf][bslot * 4]);
      GLD_LDS16(Bbase + (size_t)row * CCH + c0 + c4g * 4, &Bs[buf][bslot * 4]);
    }
  };

  // Read slot for element (row, c4): same XOR involution.
  auto compute = [&](int buf) {
    const float4* A4 = (const float4*)As[buf];
    const float4* B4 = (const float4*)Bs[buf];
    #pragma unroll
    for (int c4 = 0; c4 < 8; ++c4) {
      float4 av[8];
      #pragma unroll
      for (int ii = 0; ii < 8; ++ii) {
        int row = ii * 16 + ty;
        av[ii] = A4[row * 8 + (c4 ^ (row & 7))];
      }
      #pragma unroll
      for (int jj = 0; jj < 8; ++jj) {
        int row = jj * 16 + tx;
        float4 bv = B4[row * 8 + (c4 ^ (row & 7))];
        #pragma unroll
        for (int ii = 0; ii < 8; ++ii)
          acc[ii][jj] += av[ii].x * bv.x + av[ii].y * bv.y
                       + av[ii].z * bv.z + av[ii].w * bv.w;
      }
    }
  };

  stage(0, 0);
  asm volatile("s_waitcnt vmcnt(0)" ::: "memory");
  __syncthreads();
  #pragma unroll 1
  for (int ch = 0; ch < CHUNKS; ch += 2) {
    if (ch + 1 < CHUNKS) stage(1, ch + 1);
    compute(0);
    asm volatile("s_waitcnt vmcnt(0)" ::: "memory");
    __syncthreads();
    if (ch + 2 < CHUNKS) stage(0, ch + 2);
    compute(1);
    asm volatile("s_waitcnt vmcnt(0)" ::: "memory");
    __syncthreads();
  }

  // Fused epilogue: dist + masked 8-way relu accumulate.
  float ls = 0.0f; unsigned int lc = 0u;
  #pragma unroll
  for (int ii = 0; ii < 8; ++ii) {
    int n = n0 + ii * 16 + ty;
    float x2n = x2[m * NN + n];
    float dv[KPOS];
    #pragma unroll
    for (int p = 0; p < KPOS; ++p) dv[p] = dap[(m * NN + n) * KPOS + p];
    unsigned long long nm0 = neg_mask[n * 4 + ((k0 + tx) >> 6)];
    unsigned long long nm1 = neg_mask[n * 4 + ((k0 + 64 + tx) >> 6)];
    #pragma unroll
    for (int jj = 0; jj < 8; ++jj) {
      int k = k0 + jj * 16 + tx;
      float z = x2n + x2[m * NN + k] - 2.0f * acc[ii][jj];
      float dist = (z > 0.0f) ? sqrtf(z) : 0.0f;
      unsigned long long nm = (jj < 4) ? nm0 : nm1;
      bool isneg = (nm >> (k & 63)) & 1ull;
      if (isneg) {
        #pragma unroll
        for (int p = 0; p < KPOS; ++p) {
          float tt = MARG + dv[p] - dist;
          if (tt > 0.0f) { ls += tt; lc++; }
        }
      }
    }
  }
  #pragma unroll
  for (int off = 32; off > 0; off >>= 1) {
    ls += __shfl_down(ls, off, 64);
    lc += __shfl_down(lc, off, 64);
  }
  if ((t & 63) == 0) {   // one atomic pair per wave (4 per block)
    atomicAdd(&s_acc[m], ls);
    atomicAdd(&c_acc[m], lc);
  }
}

// Kernel C: finalize the two scalars.
__global__ void kC(const float* __restrict__ s_acc,
                   const unsigned int* __restrict__ c_acc,
                   float* __restrict__ out) {
  int t = threadIdx.x;  // 64 threads = 1 wave
  float c  = (float)c_acc[t];
  float sm = s_acc[t];
  float mean = (c > 0.0f) ? (sm / c) : 0.0f;
  float csum = c;
  #pragma unroll
  for (int off = 32; off > 0; off >>= 1) {
    mean += __shfl_down(mean, off, 64);
    csum += __shfl_down(csum, off, 64);
  }
  if (t == 0) {
    out[0] = mean / 64.0f;
    // lm.size = M * N * K * (N-K) = 64*256*8*248 = 32,505,856
    out[1] = (csum / 64.0f) / 32505856.0f;
  }
}

extern "C" void kernel_launch(void* const* d_in, const int* in_sizes, int n_in,
                              void* d_out, int out_size, void* d_ws, size_t ws_size,
                              hipStream_t stream) {
  const float* feature = (const float*)d_in[0];
  const int*   label   = (const int*)d_in[1];
  char* w = (char*)d_ws;
  float* Xt  = (float*)(w + XT_OFF);
  float* x2  = (float*)(w + X2_OFF);
  float* dap = (float*)(w + DAP_OFF);
  int*   pos = (int*)(w + POS_OFF);
  unsigned long long* neg = (unsigned long long*)(w + NEG_OFF);
  float* s_acc = (float*)(w + S_OFF);
  unsigned int* c_acc = (unsigned int*)(w + CNT_OFF);
  float* out = (float*)d_out;

  kP <<<1,    256, 0, stream>>>(label, pos, neg, s_acc, c_acc);
  kT <<<2048, 256, 0, stream>>>(feature, Xt);
  kA1<<<64,   256, 0, stream>>>(Xt, x2);
  kA2<<<512,  256, 0, stream>>>(Xt, x2, pos, dap);
  kB <<<256,  256, 0, stream>>>(Xt, x2, dap, neg, s_acc, c_acc);
  kC <<<1,    64,  0, stream>>>(s_acc, c_acc, out);
}